// Round 15
// baseline (398.413 us; speedup 1.0000x reference)
//
#include <hip/hip_runtime.h>
#include <hip/hip_bf16.h>
#include <math.h>

#define HEADS 4
#define DHEAD 64
#define HD 256
#define F_IN 256
#define NEG_SLOPE 0.2f

typedef __attribute__((ext_vector_type(8))) short bf16x8;
typedef __attribute__((ext_vector_type(8))) ushort u16x8;
typedef __attribute__((ext_vector_type(4))) float f32x4;

__device__ __forceinline__ ushort f2bf(float f) {
    __hip_bfloat16 b = __float2bfloat16(f);
    ushort u; __builtin_memcpy(&u, &b, 2);
    return u;
}

// ---------------- prep0: W->Wt permute/cast (blocks [0,256)) || zero counts ----------------
__global__ __launch_bounds__(256) void prep0_k(const float* __restrict__ W,
                                               ushort* __restrict__ Wt,
                                               int* __restrict__ counts, int N) {
    if (blockIdx.x < 256) {
        int i = blockIdx.x * 256 + threadIdx.x;   // 65536 elems, W row-major [k][c]
        int k = i >> 8, c = i & 255;
        int ct = c >> 4, kb = k >> 5, kh = (k >> 3) & 3, j = k & 7;
        int l = kh * 16 + (c & 15);
        Wt[(size_t)((ct * 8 + kb) * 64 + l) * 8 + j] = f2bf(W[i]);
    } else {
        int i = (blockIdx.x - 256) * 256 + threadIdx.x;
        if (i < N) counts[i] = 0;
    }
}

// ---------------- FUSED: gemm(Wt) blocks [0,GB)  ||  hist+pos blocks [GB,GB+HB) ----------------
// Resource diet so hist blocks get occupancy: LDS 16KB (BK=128 two-stage A),
// B streamed per-kb from L2-hot Wt (16 live b-regs), launch_bounds(256,6) caps VGPR.
#define HIST_BLOCKS 2048
__global__ __launch_bounds__(256, 6) void fused_k(const float* __restrict__ A,
                                                  const ushort* __restrict__ Wt,
                                                  const float* __restrict__ attn_l,
                                                  const float* __restrict__ attn_r,
                                                  ushort* __restrict__ hbf,
                                                  float* __restrict__ el,
                                                  float* __restrict__ er,
                                                  const int* __restrict__ dst,
                                                  int* __restrict__ counts,
                                                  unsigned char* __restrict__ pos,
                                                  int M, int E, int GB) {
    __shared__ ushort As[64 * 128];       // 16KB: [row][k-half] bf16, 256B/row, XOR ((row&7)<<4)

    if (blockIdx.x >= GB) {               // ---- histogram path (overlaps gemm) ----
        const int stride = HIST_BLOCKS * 256;
        for (int i = (blockIdx.x - GB) * 256 + threadIdx.x; i < E; i += stride)
            pos[i] = (unsigned char)atomicAdd(&counts[dst[i]], 1);
        return;
    }

    // ---- gemm path ----
    const int tid = threadIdx.x;
    const int wave = tid >> 6;
    const int lane = tid & 63;
    const int r16 = lane & 15;
    const int khalf = lane >> 4;
    const int row0 = blockIdx.x * 64;
    const int wcol0 = wave * 64;

    const int srow = tid >> 2;            // staging: row, cols cg*32..+32 of current stage
    const int cg = tid & 3;
    int arow = row0 + srow; if (arow >= M) arow = M - 1;
    const float* ap = A + (size_t)arow * F_IN;
    const int sww = (srow & 7) << 4;
    char* wb = (char*)As + srow * 256;

    f32x4 acc[4][4] = {};

#pragma unroll
    for (int s = 0; s < 2; ++s) {
        if (s) __syncthreads();           // stage-0 reads done before overwrite
#pragma unroll
        for (int q = 0; q < 2; ++q) {     // 16 cols per q
            const float* p = ap + s * 128 + cg * 32 + q * 16;
            float4 f0 = *(const float4*)(p + 0);
            float4 f1 = *(const float4*)(p + 4);
            float4 f2 = *(const float4*)(p + 8);
            float4 f3 = *(const float4*)(p + 12);
            u16x8 c0, c1;
            c0[0]=f2bf(f0.x); c0[1]=f2bf(f0.y); c0[2]=f2bf(f0.z); c0[3]=f2bf(f0.w);
            c0[4]=f2bf(f1.x); c0[5]=f2bf(f1.y); c0[6]=f2bf(f1.z); c0[7]=f2bf(f1.w);
            c1[0]=f2bf(f2.x); c1[1]=f2bf(f2.y); c1[2]=f2bf(f2.z); c1[3]=f2bf(f2.w);
            c1[4]=f2bf(f3.x); c1[5]=f2bf(f3.y); c1[6]=f2bf(f3.z); c1[7]=f2bf(f3.w);
            *(u16x8*)(wb + ((cg * 64 + q * 32 + 0)  ^ sww)) = c0;
            *(u16x8*)(wb + ((cg * 64 + q * 32 + 16) ^ sww)) = c1;
        }
        __syncthreads();

#pragma unroll
        for (int kbl = 0; kbl < 4; ++kbl) {
            const int kb = s * 4 + kbl;
            bf16x8 a[4], b[4];
#pragma unroll
            for (int mr = 0; mr < 4; ++mr) {
                const int row = mr * 16 + r16;
                const int sw = (row & 7) << 4;
                a[mr] = *(const bf16x8*)((const char*)As + row * 256 +
                                         ((kbl * 64 + khalf * 16) ^ sw));
            }
#pragma unroll
            for (int nc = 0; nc < 4; ++nc)
                b[nc] = *(const bf16x8*)(Wt + ((size_t)((wave * 4 + nc) * 8 + kb) * 64 + lane) * 8);
#pragma unroll
            for (int mr = 0; mr < 4; ++mr)
#pragma unroll
                for (int nc = 0; nc < 4; ++nc)
                    acc[mr][nc] = __builtin_amdgcn_mfma_f32_16x16x32_bf16(
                        a[mr], b[nc], acc[mr][nc], 0, 0, 0);
        }
    }

    float al[4], ar[4];
#pragma unroll
    for (int nc = 0; nc < 4; ++nc) {
        al[nc] = attn_l[wcol0 + nc * 16 + r16];
        ar[nc] = attn_r[wcol0 + nc * 16 + r16];
    }
#pragma unroll
    for (int mr = 0; mr < 4; ++mr) {
#pragma unroll
        for (int r = 0; r < 4; ++r) {
            int row = row0 + mr * 16 + khalf * 4 + r;
            float vl = 0.f, vr = 0.f;
#pragma unroll
            for (int nc = 0; nc < 4; ++nc) {
                float v = acc[mr][nc][r];
                vl = fmaf(v, al[nc], vl);
                vr = fmaf(v, ar[nc], vr);
            }
#pragma unroll
            for (int off = 1; off < 16; off <<= 1) {
                vl += __shfl_xor(vl, off);
                vr += __shfl_xor(vr, off);
            }
            if (row < M) {
                if (r16 == 0) {
                    el[row * HEADS + wave] = vl;
                    er[row * HEADS + wave] = vr;
                }
#pragma unroll
                for (int nc = 0; nc < 4; ++nc)
                    hbf[(size_t)row * HD + wcol0 + nc * 16 + r16] = f2bf(acc[mr][nc][r]);
            }
        }
    }
}

// ---------------- scan trio: counts -> row_start ----------------
#define SCAN_SPAN 4096
__global__ __launch_bounds__(1024) void blocksum_k(const int* __restrict__ counts,
                                                   int* __restrict__ btot, int N) {
    __shared__ int wsum[16];
    const int tid = threadIdx.x, lane = tid & 63, wid = tid >> 6;
    int i0 = blockIdx.x * SCAN_SPAN + tid * 4;
    int t = 0;
#pragma unroll
    for (int r = 0; r < 4; ++r) { int i = i0 + r; if (i < N) t += counts[i]; }
#pragma unroll
    for (int off = 32; off; off >>= 1) t += __shfl_xor(t, off);
    if (lane == 0) wsum[wid] = t;
    __syncthreads();
    if (tid == 0) {
        int s = 0;
        for (int w = 0; w < 16; ++w) s += wsum[w];
        btot[blockIdx.x] = s;
    }
}

__global__ __launch_bounds__(64) void scanb_k(const int* __restrict__ btot,
                                              int* __restrict__ boff, int nb) {
    int lane = threadIdx.x;
    int v = (lane < nb) ? btot[lane] : 0;
    int sc = v;
    for (int off = 1; off < 64; off <<= 1) {
        int u = __shfl_up(sc, off);
        if (lane >= off) sc += u;
    }
    if (lane < nb) boff[lane] = sc - v;
}

__global__ __launch_bounds__(1024) void scanw_k(const int* __restrict__ counts,
                                                const int* __restrict__ boff,
                                                int* __restrict__ row_start, int N) {
    __shared__ int wsum[16];
    const int tid = threadIdx.x, lane = tid & 63, wid = tid >> 6;
    int i0 = blockIdx.x * SCAN_SPAN + tid * 4;
    int v[4]; int t = 0;
#pragma unroll
    for (int r = 0; r < 4; ++r) { int i = i0 + r; v[r] = (i < N) ? counts[i] : 0; t += v[r]; }
    int sc = t;
    for (int off = 1; off < 64; off <<= 1) {
        int u = __shfl_up(sc, off);
        if (lane >= off) sc += u;
    }
    if (lane == 63) wsum[wid] = sc;
    __syncthreads();
    int wpref = 0;
    for (int w = 0; w < wid; ++w) wpref += wsum[w];
    int excl = boff[blockIdx.x] + wpref + sc - t;
    int run = 0;
#pragma unroll
    for (int r = 0; r < 4; ++r) {
        int i = i0 + r;
        if (i < N) row_start[i] = excl + run;
        run += v[r];
    }
    if (N - 1 >= i0 && N - 1 < i0 + 4) row_start[N] = excl + run;
}

// ---------------- place: NO atomics, plain random 4B write ----------------
__global__ __launch_bounds__(256) void place_k(const int* __restrict__ src,
                                               const int* __restrict__ dst,
                                               const unsigned char* __restrict__ pos,
                                               const int* __restrict__ row_start,
                                               int* __restrict__ sorted_src, int E) {
    int i = blockIdx.x * 256 + threadIdx.x;
    if (i < E)
        sorted_src[row_start[dst[i]] + (int)pos[i]] = src[i];
}

// ---------------- GAT aggregation: 4 waves/block, one node/wave, depth-4 + NT hints ----------------
__global__ __launch_bounds__(256) void gat4_k(const ushort* __restrict__ hbf,
                                              const float* __restrict__ el,
                                              const float* __restrict__ er,
                                              const float* __restrict__ bias,
                                              const int* __restrict__ row_start,
                                              const int* __restrict__ sorted_src,
                                              float* __restrict__ out, int N) {
    __shared__ int   s_idx[4][64];
    __shared__ float p_s[4][64][4];
    const int wv = threadIdx.x >> 6, lane = threadIdx.x & 63;
    const int head = lane >> 4;
    const int n = blockIdx.x * 4 + wv;
    if (n >= N) return;

    const int start = row_start[n], end = row_start[n + 1];
    const int deg = end - start;

    const float4 er4 = *(const float4*)&er[n * 4];
    const ushort* __restrict__ hrow = hbf + (unsigned)lane * 4u;

    float acc0 = 0.f, acc1 = 0.f, acc2 = 0.f, acc3 = 0.f, ssum = 0.f;

#define GLOAD(i, V, Q) { int s_ = s_idx[wv][i]; Q = p_s[wv][i][head]; \
                         V = *(const uint2*)(hrow + (size_t)(unsigned)s_ * HD); }
#define GUSE(V, Q) { union { unsigned u; float f; } b0_, b1_, b2_, b3_; \
                     b0_.u = V.x << 16; b1_.u = V.x & 0xffff0000u; \
                     b2_.u = V.y << 16; b3_.u = V.y & 0xffff0000u; \
                     acc0 = fmaf(Q, b0_.f, acc0); acc1 = fmaf(Q, b1_.f, acc1); \
                     acc2 = fmaf(Q, b2_.f, acc2); acc3 = fmaf(Q, b3_.f, acc3); \
                     ssum += Q; }

    for (int c0 = 0; c0 < deg; c0 += 64) {
        const int cnt = min(64, deg - c0);
        if (lane < cnt) {
            int s = __builtin_nontemporal_load(&sorted_src[start + c0 + lane]);
            float4 e4 = *(const float4*)&el[s * 4];
            float4 pv;
            float x0 = e4.x + er4.x; x0 = fmaxf(x0, NEG_SLOPE * x0);
            float x1 = e4.y + er4.y; x1 = fmaxf(x1, NEG_SLOPE * x1);
            float x2 = e4.z + er4.z; x2 = fmaxf(x2, NEG_SLOPE * x2);
            float x3 = e4.w + er4.w; x3 = fmaxf(x3, NEG_SLOPE * x3);
            pv.x = __expf(x0); pv.y = __expf(x1); pv.z = __expf(x2); pv.w = __expf(x3);
            s_idx[wv][lane] = s;
            *(float4*)&p_s[wv][lane][0] = pv;
        }
        __builtin_amdgcn_wave_barrier();

        int k = 0;
        if (cnt >= 8) {
            uint2 va, vb, vc, vd; float qa, qb, qc, qd;
            GLOAD(0, va, qa); GLOAD(1, vb, qb); GLOAD(2, vc, qc); GLOAD(3, vd, qd);
            for (; k + 8 <= cnt; k += 4) {
                GUSE(va, qa); GLOAD(k + 4, va, qa);
                GUSE(vb, qb); GLOAD(k + 5, vb, qb);
                GUSE(vc, qc); GLOAD(k + 6, vc, qc);
                GUSE(vd, qd); GLOAD(k + 7, vd, qd);
            }
            GUSE(va, qa); GUSE(vb, qb); GUSE(vc, qc); GUSE(vd, qd);
            k += 4;
        }
        for (; k < cnt; ++k) { uint2 v; float q; GLOAD(k, v, q); GUSE(v, q); }
        __builtin_amdgcn_wave_barrier();
    }
#undef GLOAD
#undef GUSE

    const float inv = 1.0f / fmaxf(ssum, 1e-16f);
    const float4 b4 = *(const float4*)&bias[lane * 4];
    f32x4 o;
    o[0] = fmaf(acc0, inv, b4.x);
    o[1] = fmaf(acc1, inv, b4.y);
    o[2] = fmaf(acc2, inv, b4.z);
    o[3] = fmaf(acc3, inv, b4.w);
    __builtin_nontemporal_store(o, (f32x4*)&out[(size_t)n * HD + lane * 4]);
}

extern "C" void kernel_launch(void* const* d_in, const int* in_sizes, int n_in,
                              void* d_out, int out_size, void* d_ws, size_t ws_size,
                              hipStream_t stream) {
    const float* feat   = (const float*)d_in[0];
    const float* W      = (const float*)d_in[1];
    const float* attn_l = (const float*)d_in[2];
    const float* attn_r = (const float*)d_in[3];
    const float* bias   = (const float*)d_in[4];
    const int*   src    = (const int*)d_in[5];
    const int*   dst    = (const int*)d_in[6];

    const int N = in_sizes[0] / F_IN;     // 100000
    const int E = in_sizes[5];            // 1600000

    ushort* hbf = (ushort*)d_ws;                        // N*256 bf16
    float* el = (float*)(hbf + (size_t)N * HD);         // N*4
    float* er = el + (size_t)N * HEADS;                 // N*4
    int* counts     = (int*)(er + (size_t)N * HEADS);   // N
    int* row_start  = counts + N;                       // N+1
    int* sorted_src = row_start + (N + 1);              // E
    int* btot       = sorted_src + E;                   // <=64
    int* boff       = btot + 64;                        // <=64
    unsigned char* pos = (unsigned char*)(boff + 64);   // E (uchar)
    ushort* Wt = (ushort*)(((uintptr_t)(pos + E) + 15) & ~(uintptr_t)15); // 256*256

    float* out = (float*)d_out;

    const int nb = (N + SCAN_SPAN - 1) / SCAN_SPAN;     // 25 for N=100000
    const int GB = (N + 63) / 64;                       // gemm blocks

    prep0_k<<<256 + (N + 255) / 256, 256, 0, stream>>>(W, Wt, counts, N);
    fused_k<<<GB + HIST_BLOCKS, 256, 0, stream>>>(feat, Wt, attn_l, attn_r,
                                                  hbf, el, er, dst, counts, pos, N, E, GB);

    blocksum_k<<<nb, 1024, 0, stream>>>(counts, btot, N);
    scanb_k<<<1, 64, 0, stream>>>(btot, boff, nb);
    scanw_k<<<nb, 1024, 0, stream>>>(counts, boff, row_start, N);
    place_k<<<(E + 255) / 256, 256, 0, stream>>>(src, dst, pos, row_start, sorted_src, E);

    gat4_k<<<(N + 3) / 4, 256, 0, stream>>>(hbf, el, er, bias, row_start, sorted_src, out, N);
}

// Round 16
// 283.008 us; speedup vs baseline: 1.4078x; 1.4078x over previous
//
#include <hip/hip_runtime.h>
#include <hip/hip_bf16.h>
#include <math.h>

#define HEADS 4
#define DHEAD 64
#define HD 256
#define F_IN 256
#define NEG_SLOPE 0.2f

typedef __attribute__((ext_vector_type(8))) short bf16x8;
typedef __attribute__((ext_vector_type(8))) ushort u16x8;
typedef __attribute__((ext_vector_type(4))) float f32x4;

__device__ __forceinline__ ushort f2bf(float f) {
    __hip_bfloat16 b = __float2bfloat16(f);
    ushort u; __builtin_memcpy(&u, &b, 2);
    return u;
}

// ---------------- prep0: W->Wt permute/cast (blocks [0,256)) || zero counts ----------------
__global__ __launch_bounds__(256) void prep0_k(const float* __restrict__ W,
                                               ushort* __restrict__ Wt,
                                               int* __restrict__ counts, int N) {
    if (blockIdx.x < 256) {
        int i = blockIdx.x * 256 + threadIdx.x;   // 65536 elems, W row-major [k][c]
        int k = i >> 8, c = i & 255;
        int ct = c >> 4, kb = k >> 5, kh = (k >> 3) & 3, j = k & 7;
        int l = kh * 16 + (c & 15);
        Wt[(size_t)((ct * 8 + kb) * 64 + l) * 8 + j] = f2bf(W[i]);
    } else {
        int i = (blockIdx.x - 256) * 256 + threadIdx.x;
        if (i < N) counts[i] = 0;
    }
}

// ---------------- FUSED: hist+pos blocks [0,HB)  ||  gemm(Wt) blocks [HB,HB+GB) ----------------
// Hist first: it's the longer, latency-bound workload — filling the residency window
// with hist lets gemm blocks stream in behind it, maximizing the overlap window.
#define HIST_BLOCKS 2048
__global__ __launch_bounds__(256) void fused_k(const float* __restrict__ A,
                                               const ushort* __restrict__ Wt,
                                               const float* __restrict__ attn_l,
                                               const float* __restrict__ attn_r,
                                               ushort* __restrict__ hbf,
                                               float* __restrict__ el,
                                               float* __restrict__ er,
                                               const int* __restrict__ dst,
                                               int* __restrict__ counts,
                                               ushort* __restrict__ pos,
                                               int M, int E) {
    __shared__ ushort As[64 * 256];       // [row][k] bf16, 512B/row, byte-XOR ((row&7)<<4)

    if (blockIdx.x < HIST_BLOCKS) {       // ---- histogram path (front of grid) ----
        const int stride = HIST_BLOCKS * 256;
        for (int i = blockIdx.x * 256 + threadIdx.x; i < E; i += stride)
            pos[i] = (ushort)atomicAdd(&counts[dst[i]], 1);
        return;
    }

    // ---- gemm path: B preloaded from Wt, A via LDS, one barrier, fused el/er ----
    const int tid = threadIdx.x;
    const int wave = tid >> 6;
    const int lane = tid & 63;
    const int r16 = lane & 15;
    const int khalf = lane >> 4;
    const int row0 = (blockIdx.x - HIST_BLOCKS) * 64;
    const int wcol0 = wave * 64;

    bf16x8 b[4][8];
#pragma unroll
    for (int nc = 0; nc < 4; ++nc) {
        const int ct = wave * 4 + nc;
#pragma unroll
        for (int kb = 0; kb < 8; ++kb)
            b[nc][kb] = *(const bf16x8*)(Wt + ((size_t)(ct * 8 + kb) * 64 + lane) * 8);
    }

    {
        const int srow = tid >> 2;
        const int cg = tid & 3;
        int arow = row0 + srow; if (arow >= M) arow = M - 1;
        const float* ap = A + (size_t)arow * F_IN + cg * 64;
        const int sw = (srow & 7) << 4;
        char* wb = (char*)As + srow * 512;
#pragma unroll
        for (int q = 0; q < 8; ++q) {
            float4 f0 = *(const float4*)(ap + q * 8);
            float4 f1 = *(const float4*)(ap + q * 8 + 4);
            u16x8 cv;
            cv[0] = f2bf(f0.x); cv[1] = f2bf(f0.y); cv[2] = f2bf(f0.z); cv[3] = f2bf(f0.w);
            cv[4] = f2bf(f1.x); cv[5] = f2bf(f1.y); cv[6] = f2bf(f1.z); cv[7] = f2bf(f1.w);
            *(u16x8*)(wb + ((cg * 128 + q * 16) ^ sw)) = cv;
        }
    }
    __syncthreads();

    f32x4 acc[4][4] = {};
#pragma unroll
    for (int kb = 0; kb < 8; ++kb) {
        bf16x8 a[4];
#pragma unroll
        for (int mr = 0; mr < 4; ++mr) {
            const int row = mr * 16 + r16;
            const int sw = (row & 7) << 4;
            a[mr] = *(const bf16x8*)((const char*)As + row * 512 +
                                     ((kb * 64 + khalf * 16) ^ sw));
        }
#pragma unroll
        for (int mr = 0; mr < 4; ++mr)
#pragma unroll
            for (int nc = 0; nc < 4; ++nc)
                acc[mr][nc] = __builtin_amdgcn_mfma_f32_16x16x32_bf16(
                    a[mr], b[nc][kb], acc[mr][nc], 0, 0, 0);
    }

    float al[4], ar[4];
#pragma unroll
    for (int nc = 0; nc < 4; ++nc) {
        al[nc] = attn_l[wcol0 + nc * 16 + r16];
        ar[nc] = attn_r[wcol0 + nc * 16 + r16];
    }
#pragma unroll
    for (int mr = 0; mr < 4; ++mr) {
#pragma unroll
        for (int r = 0; r < 4; ++r) {
            int row = row0 + mr * 16 + khalf * 4 + r;
            float vl = 0.f, vr = 0.f;
#pragma unroll
            for (int nc = 0; nc < 4; ++nc) {
                float v = acc[mr][nc][r];
                vl = fmaf(v, al[nc], vl);
                vr = fmaf(v, ar[nc], vr);
            }
#pragma unroll
            for (int off = 1; off < 16; off <<= 1) {
                vl += __shfl_xor(vl, off);
                vr += __shfl_xor(vr, off);
            }
            if (row < M) {
                if (r16 == 0) {
                    el[row * HEADS + wave] = vl;
                    er[row * HEADS + wave] = vr;
                }
#pragma unroll
                for (int nc = 0; nc < 4; ++nc)
                    hbf[(size_t)row * HD + wcol0 + nc * 16 + r16] = f2bf(acc[mr][nc][r]);
            }
        }
    }
}

// ---------------- scan trio: counts -> row_start ----------------
#define SCAN_SPAN 4096
__global__ __launch_bounds__(1024) void blocksum_k(const int* __restrict__ counts,
                                                   int* __restrict__ btot, int N) {
    __shared__ int wsum[16];
    const int tid = threadIdx.x, lane = tid & 63, wid = tid >> 6;
    int i0 = blockIdx.x * SCAN_SPAN + tid * 4;
    int t = 0;
#pragma unroll
    for (int r = 0; r < 4; ++r) { int i = i0 + r; if (i < N) t += counts[i]; }
#pragma unroll
    for (int off = 32; off; off >>= 1) t += __shfl_xor(t, off);
    if (lane == 0) wsum[wid] = t;
    __syncthreads();
    if (tid == 0) {
        int s = 0;
        for (int w = 0; w < 16; ++w) s += wsum[w];
        btot[blockIdx.x] = s;
    }
}

__global__ __launch_bounds__(64) void scanb_k(const int* __restrict__ btot,
                                              int* __restrict__ boff, int nb) {
    int lane = threadIdx.x;
    int v = (lane < nb) ? btot[lane] : 0;
    int sc = v;
    for (int off = 1; off < 64; off <<= 1) {
        int u = __shfl_up(sc, off);
        if (lane >= off) sc += u;
    }
    if (lane < nb) boff[lane] = sc - v;
}

__global__ __launch_bounds__(1024) void scanw_k(const int* __restrict__ counts,
                                                const int* __restrict__ boff,
                                                int* __restrict__ row_start, int N) {
    __shared__ int wsum[16];
    const int tid = threadIdx.x, lane = tid & 63, wid = tid >> 6;
    int i0 = blockIdx.x * SCAN_SPAN + tid * 4;
    int v[4]; int t = 0;
#pragma unroll
    for (int r = 0; r < 4; ++r) { int i = i0 + r; v[r] = (i < N) ? counts[i] : 0; t += v[r]; }
    int sc = t;
    for (int off = 1; off < 64; off <<= 1) {
        int u = __shfl_up(sc, off);
        if (lane >= off) sc += u;
    }
    if (lane == 63) wsum[wid] = sc;
    __syncthreads();
    int wpref = 0;
    for (int w = 0; w < wid; ++w) wpref += wsum[w];
    int excl = boff[blockIdx.x] + wpref + sc - t;
    int run = 0;
#pragma unroll
    for (int r = 0; r < 4; ++r) {
        int i = i0 + r;
        if (i < N) row_start[i] = excl + run;
        run += v[r];
    }
    if (N - 1 >= i0 && N - 1 < i0 + 4) row_start[N] = excl + run;
}

// ---------------- place: NO atomics, plain random 4B write ----------------
__global__ __launch_bounds__(256) void place_k(const int* __restrict__ src,
                                               const int* __restrict__ dst,
                                               const ushort* __restrict__ pos,
                                               const int* __restrict__ row_start,
                                               int* __restrict__ sorted_src, int E) {
    int i = blockIdx.x * 256 + threadIdx.x;
    if (i < E)
        sorted_src[row_start[dst[i]] + (int)pos[i]] = src[i];
}

// ---------------- GAT aggregation: 4 waves/block, one node/wave, depth-4 + NT hints ----------------
__global__ __launch_bounds__(256) void gat4_k(const ushort* __restrict__ hbf,
                                              const float* __restrict__ el,
                                              const float* __restrict__ er,
                                              const float* __restrict__ bias,
                                              const int* __restrict__ row_start,
                                              const int* __restrict__ sorted_src,
                                              float* __restrict__ out, int N) {
    __shared__ int   s_idx[4][64];
    __shared__ float p_s[4][64][4];
    const int wv = threadIdx.x >> 6, lane = threadIdx.x & 63;
    const int head = lane >> 4;
    const int n = blockIdx.x * 4 + wv;
    if (n >= N) return;

    const int start = row_start[n], end = row_start[n + 1];
    const int deg = end - start;

    const float4 er4 = *(const float4*)&er[n * 4];
    const ushort* __restrict__ hrow = hbf + (unsigned)lane * 4u;

    float acc0 = 0.f, acc1 = 0.f, acc2 = 0.f, acc3 = 0.f, ssum = 0.f;

#define GLOAD(i, V, Q) { int s_ = s_idx[wv][i]; Q = p_s[wv][i][head]; \
                         V = *(const uint2*)(hrow + (size_t)(unsigned)s_ * HD); }
#define GUSE(V, Q) { union { unsigned u; float f; } b0_, b1_, b2_, b3_; \
                     b0_.u = V.x << 16; b1_.u = V.x & 0xffff0000u; \
                     b2_.u = V.y << 16; b3_.u = V.y & 0xffff0000u; \
                     acc0 = fmaf(Q, b0_.f, acc0); acc1 = fmaf(Q, b1_.f, acc1); \
                     acc2 = fmaf(Q, b2_.f, acc2); acc3 = fmaf(Q, b3_.f, acc3); \
                     ssum += Q; }

    for (int c0 = 0; c0 < deg; c0 += 64) {
        const int cnt = min(64, deg - c0);
        if (lane < cnt) {
            int s = __builtin_nontemporal_load(&sorted_src[start + c0 + lane]);
            float4 e4 = *(const float4*)&el[s * 4];
            float4 pv;
            float x0 = e4.x + er4.x; x0 = fmaxf(x0, NEG_SLOPE * x0);
            float x1 = e4.y + er4.y; x1 = fmaxf(x1, NEG_SLOPE * x1);
            float x2 = e4.z + er4.z; x2 = fmaxf(x2, NEG_SLOPE * x2);
            float x3 = e4.w + er4.w; x3 = fmaxf(x3, NEG_SLOPE * x3);
            pv.x = __expf(x0); pv.y = __expf(x1); pv.z = __expf(x2); pv.w = __expf(x3);
            s_idx[wv][lane] = s;
            *(float4*)&p_s[wv][lane][0] = pv;
        }
        __builtin_amdgcn_wave_barrier();

        int k = 0;
        if (cnt >= 8) {
            uint2 va, vb, vc, vd; float qa, qb, qc, qd;
            GLOAD(0, va, qa); GLOAD(1, vb, qb); GLOAD(2, vc, qc); GLOAD(3, vd, qd);
            for (; k + 8 <= cnt; k += 4) {
                GUSE(va, qa); GLOAD(k + 4, va, qa);
                GUSE(vb, qb); GLOAD(k + 5, vb, qb);
                GUSE(vc, qc); GLOAD(k + 6, vc, qc);
                GUSE(vd, qd); GLOAD(k + 7, vd, qd);
            }
            GUSE(va, qa); GUSE(vb, qb); GUSE(vc, qc); GUSE(vd, qd);
            k += 4;
        }
        for (; k < cnt; ++k) { uint2 v; float q; GLOAD(k, v, q); GUSE(v, q); }
        __builtin_amdgcn_wave_barrier();
    }
#undef GLOAD
#undef GUSE

    const float inv = 1.0f / fmaxf(ssum, 1e-16f);
    const float4 b4 = *(const float4*)&bias[lane * 4];
    f32x4 o;
    o[0] = fmaf(acc0, inv, b4.x);
    o[1] = fmaf(acc1, inv, b4.y);
    o[2] = fmaf(acc2, inv, b4.z);
    o[3] = fmaf(acc3, inv, b4.w);
    __builtin_nontemporal_store(o, (f32x4*)&out[(size_t)n * HD + lane * 4]);
}

extern "C" void kernel_launch(void* const* d_in, const int* in_sizes, int n_in,
                              void* d_out, int out_size, void* d_ws, size_t ws_size,
                              hipStream_t stream) {
    const float* feat   = (const float*)d_in[0];
    const float* W      = (const float*)d_in[1];
    const float* attn_l = (const float*)d_in[2];
    const float* attn_r = (const float*)d_in[3];
    const float* bias   = (const float*)d_in[4];
    const int*   src    = (const int*)d_in[5];
    const int*   dst    = (const int*)d_in[6];

    const int N = in_sizes[0] / F_IN;     // 100000
    const int E = in_sizes[5];            // 1600000

    ushort* hbf = (ushort*)d_ws;                        // N*256 bf16
    float* el = (float*)(hbf + (size_t)N * HD);         // N*4
    float* er = el + (size_t)N * HEADS;                 // N*4
    int* counts     = (int*)(er + (size_t)N * HEADS);   // N
    int* row_start  = counts + N;                       // N+1
    int* sorted_src = row_start + (N + 1);              // E
    int* btot       = sorted_src + E;                   // <=64
    int* boff       = btot + 64;                        // <=64
    ushort* pos     = (ushort*)(boff + 64);             // E (ushort)
    ushort* Wt = (ushort*)(((uintptr_t)(pos + E) + 15) & ~(uintptr_t)15); // 256*256

    float* out = (float*)d_out;

    const int nb = (N + SCAN_SPAN - 1) / SCAN_SPAN;     // 25 for N=100000
    const int GB = (N + 63) / 64;                       // gemm blocks

    prep0_k<<<256 + (N + 255) / 256, 256, 0, stream>>>(W, Wt, counts, N);
    fused_k<<<HIST_BLOCKS + GB, 256, 0, stream>>>(feat, Wt, attn_l, attn_r,
                                                  hbf, el, er, dst, counts, pos, N, E);

    blocksum_k<<<nb, 1024, 0, stream>>>(counts, btot, N);
    scanb_k<<<1, 64, 0, stream>>>(btot, boff, nb);
    scanw_k<<<nb, 1024, 0, stream>>>(counts, boff, row_start, N);
    place_k<<<(E + 255) / 256, 256, 0, stream>>>(src, dst, pos, row_start, sorted_src, E);

    gat4_k<<<(N + 3) / 4, 256, 0, stream>>>(hbf, el, er, bias, row_start, sorted_src, out, N);
}